// Round 2
// baseline (128.587 us; speedup 1.0000x reference)
//
#include <hip/hip_runtime.h>
#include <math.h>

typedef unsigned short u16;
typedef unsigned int   u32;
typedef __attribute__((ext_vector_type(8))) short bf16x8;
typedef __attribute__((ext_vector_type(4))) float f32x4;

#define NB 8
#define NC 512
#define NS 1024
#define NH 8
#define ND 64
#define NG 32
#define CPG 16

__device__ __forceinline__ u16 f2bf(float x) {
  u32 u = __builtin_bit_cast(u32, x);
  u = u + 0x7fffu + ((u >> 16) & 1u);
  return (u16)(u >> 16);
}

__device__ __forceinline__ void gll16(void* l, const void* g) {
  __builtin_amdgcn_global_load_lds((const __attribute__((address_space(1))) void*)g,
                                   (__attribute__((address_space(3))) void*)l, 16, 0, 0);
}

__device__ __forceinline__ void drain_vm() {
  asm volatile("s_waitcnt vmcnt(0)" ::: "memory");
}

// ---------------- K0: weight fp32 -> bf16 ----------------
__global__ __launch_bounds__(256) void wconv_kernel(const float* __restrict__ qkvw,
                                                    const float* __restrict__ outw,
                                                    u16* __restrict__ wq,
                                                    u16* __restrict__ wo) {
  int i = (blockIdx.x * 256 + threadIdx.x) * 4;
  const int NQ = 3 * NC * NC;  // 786432
  const float* src;
  u16* dst;
  int off;
  if (i < NQ) { src = qkvw; dst = wq; off = i; }
  else        { src = outw; dst = wo; off = i - NQ; }
  float4 v = *(const float4*)(src + off);
  u32 lo = (u32)f2bf(v.x) | ((u32)f2bf(v.y) << 16);
  u32 hi = (u32)f2bf(v.z) | ((u32)f2bf(v.w) << 16);
  u32* p = (u32*)(dst + off);
  p[0] = lo; p[1] = hi;
}

// ---------------- K1: GroupNorm -> xnT[b][p][c] bf16 ----------------
__global__ __launch_bounds__(256) void gn_kernel(const float* __restrict__ x,
                                                 const float* __restrict__ gamma,
                                                 const float* __restrict__ beta,
                                                 u16* __restrict__ xnT) {
  __shared__ float red[10];
  const int t = threadIdx.x;
  const int wave = t >> 6, lane = t & 63;
  const int b = blockIdx.x >> 5, g = blockIdx.x & 31;
  const float* xb = x + (size_t)(b * NC + g * CPG) * NS;

  float s = 0.f, ss = 0.f;
#pragma unroll
  for (int i = 0; i < 16; ++i) {
    int idx = t + i * 256;  // float4 index over 16 ch x 1024 px
    float4 v = ((const float4*)xb)[idx];
    s  += (v.x + v.y) + (v.z + v.w);
    ss += (v.x * v.x + v.y * v.y) + (v.z * v.z + v.w * v.w);
  }
#pragma unroll
  for (int m2 = 32; m2; m2 >>= 1) { s += __shfl_xor(s, m2); ss += __shfl_xor(ss, m2); }
  if (lane == 0) { red[wave] = s; red[4 + wave] = ss; }
  __syncthreads();
  if (t == 0) {
    float fs  = (red[0] + red[1]) + (red[2] + red[3]);
    float fss = (red[4] + red[5]) + (red[6] + red[7]);
    float mean = fs * (1.f / 16384.f);
    float var  = fss * (1.f / 16384.f) - mean * mean;
    red[8] = mean;
    red[9] = rsqrtf(fmaxf(var, 0.f) + 1e-5f);
  }
  __syncthreads();
  const float mean = red[8], inv = red[9];
  float gm[CPG], bt[CPG];
#pragma unroll
  for (int ci = 0; ci < CPG; ++ci) {
    float ga = gamma[g * CPG + ci];
    gm[ci] = ga * inv;
    bt[ci] = beta[g * CPG + ci] - mean * inv * ga;
  }
  // pass 2: re-read (L2-hot), normalize, write transposed 32B chunks
#pragma unroll
  for (int i = 0; i < 4; ++i) {
    int p = t + i * 256;
    u32 pk[8];
#pragma unroll
    for (int ci = 0; ci < CPG; ci += 2) {
      float v0 = xb[(size_t)ci * NS + p]       * gm[ci]     + bt[ci];
      float v1 = xb[(size_t)(ci + 1) * NS + p] * gm[ci + 1] + bt[ci + 1];
      pk[ci >> 1] = (u32)f2bf(v0) | ((u32)f2bf(v1) << 16);
    }
    u32* dst = (u32*)(xnT + (size_t)(b * NS + p) * NC + g * CPG);
#pragma unroll
    for (int q2 = 0; q2 < 8; ++q2) dst[q2] = pk[q2];
  }
}

// ---------------- K2: QKV gemm_bt ----------------
// C[o,p] = sum_c Wq[o,c]*xnT[p,c] + bias; scatter to q/k/v buffers
__global__ __launch_bounds__(256) void qkv_gemm(const u16* __restrict__ A,
                                                const u16* __restrict__ BT,
                                                const float* __restrict__ bias,
                                                u16* __restrict__ qb,
                                                u16* __restrict__ kb,
                                                u16* __restrict__ vb) {
  __shared__ u16 lds[8192];  // A-tile bytes [0,8K), B-tile [8K,16K)
  const int t = threadIdx.x, wave = t >> 6, lane = t & 63;
  const int bn = blockIdx.x * 128;
  const int bm = blockIdx.y * 128;
  const int bb = blockIdx.z;
  const u16* Bt = BT + (size_t)bb * NS * NC;
  const int wm = wave >> 1, wn = wave & 1;
  f32x4 zero = {0.f, 0.f, 0.f, 0.f};
  f32x4 acc[4][4];
#pragma unroll
  for (int i = 0; i < 4; ++i)
#pragma unroll
    for (int j = 0; j < 4; ++j) acc[i][j] = zero;

  for (int k0 = 0; k0 < NC; k0 += 32) {
#pragma unroll
    for (int call = 0; call < 2; ++call) {
      int c = call * 256 + t;
      int row = c >> 2;
      int chs = (c & 3) ^ ((c >> 3) & 3);  // source pre-swizzle
      char* db = (char*)lds + call * 4096 + wave * 1024;
      gll16(db,        (const void*)(A  + (size_t)(bm + row) * NC + k0 + chs * 8));
      gll16(db + 8192, (const void*)(Bt + (size_t)(bn + row) * NC + k0 + chs * 8));
    }
    drain_vm();
    __syncthreads();
    bf16x8 af[4], bfr[4];
#pragma unroll
    for (int mf = 0; mf < 4; ++mf) {
      int row = wm * 64 + mf * 16 + (lane & 15);
      int cb = ((lane >> 4) * 16) ^ (((row >> 1) & 3) << 4);
      af[mf] = *(const bf16x8*)((const char*)lds + row * 64 + cb);
    }
#pragma unroll
    for (int nf = 0; nf < 4; ++nf) {
      int row = wn * 64 + nf * 16 + (lane & 15);
      int cb = ((lane >> 4) * 16) ^ (((row >> 1) & 3) << 4);
      bfr[nf] = *(const bf16x8*)((const char*)lds + 8192 + row * 64 + cb);
    }
#pragma unroll
    for (int mf = 0; mf < 4; ++mf)
#pragma unroll
      for (int nf = 0; nf < 4; ++nf)
        acc[mf][nf] = __builtin_amdgcn_mfma_f32_16x16x32_bf16(af[mf], bfr[nf], acc[mf][nf], 0, 0, 0);
    __syncthreads();
  }
  // epilogue: o -> (head n, r); r<64:Q, <128:K, else V
#pragma unroll
  for (int mf = 0; mf < 4; ++mf) {
#pragma unroll
    for (int j = 0; j < 4; ++j) {
      int o = bm + wm * 64 + mf * 16 + (lane >> 4) * 4 + j;
      int n = o / 192;
      int r = o - n * 192;
      float bv = bias[o];
      size_t hb = (size_t)(bb * NH + n);
#pragma unroll
      for (int nf = 0; nf < 4; ++nf) {
        int p = bn + wn * 64 + nf * 16 + (lane & 15);
        u16 h = f2bf(acc[mf][nf][j] + bv);
        if (r < 64)       qb[(hb * NS + p) * ND + r] = h;
        else if (r < 128) kb[(hb * NS + p) * ND + (r - 64)] = h;
        else              vb[(hb * ND + (r - 128)) * NS + p] = h;
      }
    }
  }
}

// ---------------- K3: flash attention per (qblock, b*8+n) ----------------
__global__ __launch_bounds__(256) void attn_kernel(const u16* __restrict__ qbuf,
                                                   const u16* __restrict__ kbuf,
                                                   const u16* __restrict__ vbuf,
                                                   u16* __restrict__ aoT) {
  __shared__ u16 ldsk[4096], ldsv[4096], ldsp[4096];  // 8KB each
  const int t = threadIdx.x, wave = t >> 6, lane = t & 63;
  const int qblk = blockIdx.x;   // 16 blocks of 64 q rows
  const int bn = blockIdx.y;     // b*8+n
  const int b = bn >> 3, n = bn & 7;
  const u16* qp = qbuf + (size_t)bn * NS * ND;
  const u16* kp = kbuf + (size_t)bn * NS * ND;
  const u16* vp = vbuf + (size_t)bn * ND * NS;

  bf16x8 aq[2];
  {
    int qrow = qblk * 64 + wave * 16 + (lane & 15);
#pragma unroll
    for (int ks = 0; ks < 2; ++ks)
      aq[ks] = *(const bf16x8*)(qp + (size_t)qrow * ND + ks * 32 + (lane >> 4) * 8);
  }
  float m[4], l[4];
  f32x4 zero = {0.f, 0.f, 0.f, 0.f};
  f32x4 oacc[4];
#pragma unroll
  for (int j = 0; j < 4; ++j) { m[j] = -INFINITY; l[j] = 0.f; }
#pragma unroll
  for (int df = 0; df < 4; ++df) oacc[df] = zero;

  for (int kb = 0; kb < 16; ++kb) {
#pragma unroll
    for (int call = 0; call < 2; ++call) {
      int c = call * 256 + t;
      int row = c >> 3;
      int chs = (c & 7) ^ (row & 7);  // source pre-swizzle (128B rows)
      char* dk = (char*)ldsk + call * 4096 + wave * 1024;
      char* dv = (char*)ldsv + call * 4096 + wave * 1024;
      gll16(dk, (const void*)(kp + (size_t)(kb * 64 + row) * ND + chs * 8));
      gll16(dv, (const void*)(vp + (size_t)row * NS + kb * 64 + chs * 8));
    }
    drain_vm();
    __syncthreads();
    // S = (Q K^T) * scale, C-layout: col=q? no: row(reg)=q, col(lane&15)=s'
    f32x4 sacc[4];
#pragma unroll
    for (int cf = 0; cf < 4; ++cf) sacc[cf] = zero;
#pragma unroll
    for (int ks = 0; ks < 2; ++ks)
#pragma unroll
      for (int cf = 0; cf < 4; ++cf) {
        int srow = cf * 16 + (lane & 15);
        int cb = (ks * 64 + (lane >> 4) * 16) ^ ((srow & 7) << 4);
        bf16x8 bk = *(const bf16x8*)((const char*)ldsk + srow * 128 + cb);
        sacc[cf] = __builtin_amdgcn_mfma_f32_16x16x32_bf16(aq[ks], bk, sacc[cf], 0, 0, 0);
      }
    // online softmax, q-rows live per 16-lane group (j indexes 4 rows)
    float sc[4];
#pragma unroll
    for (int j = 0; j < 4; ++j) {
      float mx = fmaxf(fmaxf(sacc[0][j], sacc[1][j]), fmaxf(sacc[2][j], sacc[3][j])) * 0.125f;
#pragma unroll
      for (int msk = 1; msk < 16; msk <<= 1) mx = fmaxf(mx, __shfl_xor(mx, msk));
      float mn = fmaxf(m[j], mx);
      sc[j] = __expf(m[j] - mn);
      m[j] = mn;
      float sum = 0.f;
#pragma unroll
      for (int cf = 0; cf < 4; ++cf) {
        float pv = __expf(sacc[cf][j] * 0.125f - mn);
        sacc[cf][j] = pv;
        sum += pv;
      }
#pragma unroll
      for (int msk = 1; msk < 16; msk <<= 1) sum += __shfl_xor(sum, msk);
      l[j] = l[j] * sc[j] + sum;
    }
#pragma unroll
    for (int df = 0; df < 4; ++df) {
      f32x4 o2 = oacc[df];
      o2[0] *= sc[0]; o2[1] *= sc[1]; o2[2] *= sc[2]; o2[3] *= sc[3];
      oacc[df] = o2;
    }
    // P -> LDS (wave-private rows), XOR-swizzled
#pragma unroll
    for (int cf = 0; cf < 4; ++cf)
#pragma unroll
      for (int j = 0; j < 4; ++j) {
        int row = wave * 16 + (lane >> 4) * 4 + j;
        int cbyte = ((cf * 16 + (lane & 15)) * 2) ^ ((row & 7) << 4);
        *(u16*)((char*)ldsp + row * 128 + cbyte) = f2bf(sacc[cf][j]);
      }
    __syncthreads();  // defensive: order P-writes vs PV reads across scheduler variance
    // O += P V
#pragma unroll
    for (int ks = 0; ks < 2; ++ks) {
      int prow = wave * 16 + (lane & 15);
      int pcb = (ks * 64 + (lane >> 4) * 16) ^ ((prow & 7) << 4);
      bf16x8 pa = *(const bf16x8*)((const char*)ldsp + prow * 128 + pcb);
#pragma unroll
      for (int df = 0; df < 4; ++df) {
        int drow = df * 16 + (lane & 15);
        int vcb = (ks * 64 + (lane >> 4) * 16) ^ ((drow & 7) << 4);
        bf16x8 bv = *(const bf16x8*)((const char*)ldsv + drow * 128 + vcb);
        oacc[df] = __builtin_amdgcn_mfma_f32_16x16x32_bf16(pa, bv, oacc[df], 0, 0, 0);
      }
    }
    __syncthreads();
  }
#pragma unroll
  for (int j = 0; j < 4; ++j) l[j] = 1.f / l[j];
#pragma unroll
  for (int df = 0; df < 4; ++df)
#pragma unroll
    for (int j = 0; j < 4; ++j) {
      int p = qblk * 64 + wave * 16 + (lane >> 4) * 4 + j;
      int d = df * 16 + (lane & 15);
      aoT[(size_t)(b * NS + p) * NC + n * ND + d] = f2bf(oacc[df][j] * l[j]);
    }
}

// ---------------- K4: out gemm_bt + bias + residual ----------------
__global__ __launch_bounds__(256) void out_gemm(const u16* __restrict__ A,
                                                const u16* __restrict__ BT,
                                                const float* __restrict__ bias,
                                                const float* __restrict__ xres,
                                                float* __restrict__ out) {
  __shared__ u16 lds[8192];
  const int t = threadIdx.x, wave = t >> 6, lane = t & 63;
  const int bn = blockIdx.x * 128;
  const int bm = blockIdx.y * 128;
  const int bb = blockIdx.z;
  const u16* Bt = BT + (size_t)bb * NS * NC;
  const int wm = wave >> 1, wn = wave & 1;
  f32x4 zero = {0.f, 0.f, 0.f, 0.f};
  f32x4 acc[4][4];
#pragma unroll
  for (int i = 0; i < 4; ++i)
#pragma unroll
    for (int j = 0; j < 4; ++j) acc[i][j] = zero;

  for (int k0 = 0; k0 < NC; k0 += 32) {
#pragma unroll
    for (int call = 0; call < 2; ++call) {
      int c = call * 256 + t;
      int row = c >> 2;
      int chs = (c & 3) ^ ((c >> 3) & 3);
      char* db = (char*)lds + call * 4096 + wave * 1024;
      gll16(db,        (const void*)(A  + (size_t)(bm + row) * NC + k0 + chs * 8));
      gll16(db + 8192, (const void*)(Bt + (size_t)(bn + row) * NC + k0 + chs * 8));
    }
    drain_vm();
    __syncthreads();
    bf16x8 af[4], bfr[4];
#pragma unroll
    for (int mf = 0; mf < 4; ++mf) {
      int row = wm * 64 + mf * 16 + (lane & 15);
      int cb = ((lane >> 4) * 16) ^ (((row >> 1) & 3) << 4);
      af[mf] = *(const bf16x8*)((const char*)lds + row * 64 + cb);
    }
#pragma unroll
    for (int nf = 0; nf < 4; ++nf) {
      int row = wn * 64 + nf * 16 + (lane & 15);
      int cb = ((lane >> 4) * 16) ^ (((row >> 1) & 3) << 4);
      bfr[nf] = *(const bf16x8*)((const char*)lds + 8192 + row * 64 + cb);
    }
#pragma unroll
    for (int mf = 0; mf < 4; ++mf)
#pragma unroll
      for (int nf = 0; nf < 4; ++nf)
        acc[mf][nf] = __builtin_amdgcn_mfma_f32_16x16x32_bf16(af[mf], bfr[nf], acc[mf][nf], 0, 0, 0);
    __syncthreads();
  }
#pragma unroll
  for (int mf = 0; mf < 4; ++mf) {
#pragma unroll
    for (int j = 0; j < 4; ++j) {
      int o = bm + wm * 64 + mf * 16 + (lane >> 4) * 4 + j;
      float bv = bias[o];
#pragma unroll
      for (int nf = 0; nf < 4; ++nf) {
        int p = bn + wn * 64 + nf * 16 + (lane & 15);
        size_t idx = (size_t)(bb * NC + o) * NS + p;
        out[idx] = acc[mf][nf][j] + bv + xres[idx];
      }
    }
  }
}

extern "C" void kernel_launch(void* const* d_in, const int* in_sizes, int n_in,
                              void* d_out, int out_size, void* d_ws, size_t ws_size,
                              hipStream_t stream) {
  const float* x     = (const float*)d_in[0];
  const float* gn_w  = (const float*)d_in[1];
  const float* gn_b  = (const float*)d_in[2];
  const float* qkv_w = (const float*)d_in[3];
  const float* qkv_b = (const float*)d_in[4];
  const float* out_w = (const float*)d_in[5];
  const float* out_b = (const float*)d_in[6];
  float* out = (float*)d_out;
  char* ws = (char*)d_ws;

  // Workspace layout (26 MB total; was 44 MB — defend against ws_size limits):
  //   wq  [0,        1.5MB)
  //   wo  [1.5MB,    2MB)
  //   xnT [2MB,     10MB)   -- dead after qkv_gemm; aoT REUSES this region
  //   kb  [10MB,    18MB)
  //   vb  [18MB,    26MB)
  //   qb lives in d_out[0:8MB) (d_out is 16MB fp32; fully rewritten by out_gemm last)
  u16* wq  = (u16*)(ws);
  u16* wo  = (u16*)(ws + 1572864);
  u16* xnT = (u16*)(ws + 2097152);
  u16* kb  = (u16*)(ws + 10485760);
  u16* vb  = (u16*)(ws + 18874368);
  u16* aoT = (u16*)(ws + 2097152);   // overlaps xnT (sequentially dead)
  u16* qb  = (u16*)d_out;            // scratch use of d_out; overwritten by out_gemm

  wconv_kernel<<<dim3(1024), dim3(256), 0, stream>>>(qkv_w, out_w, wq, wo);
  gn_kernel<<<dim3(NB * NG), dim3(256), 0, stream>>>(x, gn_w, gn_b, xnT);
  qkv_gemm<<<dim3(8, 12, NB), dim3(256), 0, stream>>>(wq, xnT, qkv_b, qb, kb, vb);
  attn_kernel<<<dim3(16, NB * NH), dim3(256), 0, stream>>>(qb, kb, vb, aoT);
  out_gemm<<<dim3(8, 4, NB), dim3(256), 0, stream>>>(wo, aoT, out_b, x, out);
}